// Round 2
// baseline (203.176 us; speedup 1.0000x reference)
//
#include <hip/hip_runtime.h>
#include <math.h>

#define N_NODES 131072
#define G_GRP   512
#define TPB     128
#define SPAN    32

// d_ws float offsets
#define ACC_OFF   0        // 3072 floats (512 groups * 6)
#define PG1_OFF   4096     // 8192 floats: [u4][j][du]  (Wg1 packed)
#define PC_OFF    12288    // 6144 floats: [j][out=c*16+h] (Wg2 * wpost combos)
#define CB_OFF    18432    // 96 floats   (bg2 * wpost combos)
#define P0_OFF    18560    // 2048 floats: [u4][h][du] (W0)
#define P1_OFF    20608    // 1024 floats: [u4][h][du] (W1)
#define P2_OFF    21632    // 512 floats : [u4][h][du] (W2)
#define BG1_OFF   22144    // 64 floats

__global__ __launch_bounds__(256) void repack_kernel(
    const float* __restrict__ W0, const float* __restrict__ W1,
    const float* __restrict__ W2, const float* __restrict__ Wg1,
    const float* __restrict__ bg1, const float* __restrict__ Wg2,
    const float* __restrict__ bg2, const float* __restrict__ wp0,
    const float* __restrict__ wp2, float* __restrict__ ws)
{
  int i = blockIdx.x * 256 + threadIdx.x;
  if (i < 8192) {               // PG1[u4*256 + j*4 + du] = Wg1[(4u4+du)][j]
    int du = i & 3, j = (i >> 2) & 63, u4 = i >> 8;
    ws[PG1_OFF + i] = Wg1[(u4 * 4 + du) * 64 + j];
  }
  if (i < 6144) {               // PC[j*96 + out]
    int out = i % 96, j = i / 96;
    int cidx = out >> 4, h = out & 15;
    const float* row = Wg2 + j * 144;
    float v;
    switch (cidx) {
      case 0:  v = wp0[0] * row[h];        break;   // w[:,0] -> o0 s^2
      case 1:  v = wp0[1] * row[32 + h];   break;   // w[:,2] -> o0 |v|^2
      case 2:  v = wp0[2] * row[96 + h];   break;   // w[:,6] -> o0 |t|^2
      case 3:  v = wp2[0] * row[16 + h] + wp2[2] * row[80 + h]; break; // s*t5
      case 4:  v = wp2[1] * row[64 + h];   break;   // vv5
      default: v = wp2[3] * row[128 + h];  break;   // tt5
    }
    ws[PC_OFF + i] = v;
  }
  if (i < 2048) {
    int du = i & 3, h = (i >> 2) & 15, u4 = i >> 6;
    ws[P0_OFF + i] = W0[(u4 * 4 + du) * 16 + h];
  }
  if (i < 1024) {
    int du = i & 3, h = (i >> 2) & 15, u4 = i >> 6;
    ws[P1_OFF + i] = W1[(u4 * 4 + du) * 16 + h];
  }
  if (i < 512) {
    int du = i & 3, h = (i >> 2) & 15, u4 = i >> 6;
    ws[P2_OFF + i] = W2[(u4 * 4 + du) * 16 + h];
  }
  if (i < 96) {
    int cidx = i >> 4, h = i & 15;
    float v;
    switch (cidx) {
      case 0:  v = wp0[0] * bg2[h];        break;
      case 1:  v = wp0[1] * bg2[32 + h];   break;
      case 2:  v = wp0[2] * bg2[96 + h];   break;
      case 3:  v = wp2[0] * bg2[16 + h] + wp2[2] * bg2[80 + h]; break;
      case 4:  v = wp2[1] * bg2[64 + h];   break;
      default: v = wp2[3] * bg2[128 + h];  break;
    }
    ws[CB_OFF + i] = v;
  }
  if (i < 64) ws[BG1_OFF + i] = bg1[i];
}

__global__ __launch_bounds__(TPB, 2) void node_kernel(
    const float* __restrict__ xsc, const float* __restrict__ xsp,
    const int* __restrict__ bidx, float* __restrict__ ws)
{
  __shared__ float hidL[TPB * 65];
  __shared__ float accL[SPAN * 6];
  const int tid = threadIdx.x;
  const int node = blockIdx.x * TPB + tid;

  for (int i = tid; i < SPAN * 6; i += TPB) accL[i] = 0.f;
  __syncthreads();

  const float SQ2 = 1.41421356237f;
  const float I2  = 0.70710678118f;
  const float I6  = 0.40824829046f;

  // ---------- gate1: hid = silu(x_scalar @ Wg1 + bg1) ----------
  float hid[64];
  {
    const float* __restrict__ BG1 = ws + BG1_OFF;
#pragma unroll
    for (int j = 0; j < 64; ++j) hid[j] = BG1[j];
    const float4* __restrict__ xp = (const float4*)(xsc + (size_t)node * 128);
    const float4* __restrict__ wg = (const float4*)(ws + PG1_OFF);
    for (int u4 = 0; u4 < 32; ++u4) {
      float4 x4 = xp[u4];
      const float4* __restrict__ wrow = wg + (u4 << 6);
#pragma unroll
      for (int j = 0; j < 64; ++j) {
        float4 w = wrow[j];
        hid[j] = fmaf(x4.x, w.x, fmaf(x4.y, w.y, fmaf(x4.z, w.z, fmaf(x4.w, w.w, hid[j]))));
      }
    }
#pragma unroll
    for (int j = 0; j < 64; ++j) {
      float hh = hid[j];
      float sg = hh / (1.f + __expf(-hh));   // silu
      hidL[tid * 65 + j] = sg;
    }
  }

  // ---------- c-phase: c[out] = CB[out] + sum_j hid[j]*PC[j][out] ----------
  float c[96];
  {
    const float4* __restrict__ cb4 = (const float4*)(ws + CB_OFF);
#pragma unroll
    for (int o4 = 0; o4 < 24; ++o4) {
      float4 b = cb4[o4];
      c[4*o4] = b.x; c[4*o4+1] = b.y; c[4*o4+2] = b.z; c[4*o4+3] = b.w;
    }
    const float4* __restrict__ pc = (const float4*)(ws + PC_OFF);
    for (int j = 0; j < 64; ++j) {
      float hj = hidL[tid * 65 + j];
      const float4* __restrict__ row = pc + j * 24;
#pragma unroll
      for (int o4 = 0; o4 < 24; ++o4) {
        float4 w = row[o4];
        c[4*o4]   = fmaf(hj, w.x, c[4*o4]);
        c[4*o4+1] = fmaf(hj, w.y, c[4*o4+1]);
        c[4*o4+2] = fmaf(hj, w.z, c[4*o4+2]);
        c[4*o4+3] = fmaf(hj, w.w, c[4*o4+3]);
      }
    }
  }

  float o0 = 0.f;
  float o2m0 = 0.f, o2m1 = 0.f, o2m2 = 0.f, o2m3 = 0.f, o2m4 = 0.f;

  // ---------- s-phase ----------
  {
    float s[16];
#pragma unroll
    for (int h = 0; h < 16; ++h) s[h] = 0.f;
    const float4* __restrict__ xp = (const float4*)(xsp + (size_t)node * 480);
    const float4* __restrict__ p0 = (const float4*)(ws + P0_OFF);
    for (int u4 = 0; u4 < 32; ++u4) {
      float4 x4 = xp[u4];
      const float4* __restrict__ row = p0 + (u4 << 4);
#pragma unroll
      for (int h = 0; h < 16; ++h) {
        float4 w = row[h];
        s[h] = fmaf(x4.x, w.x, fmaf(x4.y, w.y, fmaf(x4.z, w.z, fmaf(x4.w, w.w, s[h]))));
      }
    }
#pragma unroll
    for (int h = 0; h < 16; ++h) {
      o0 = fmaf(c[h] * s[h], s[h], o0);   // c0*s^2
      c[48 + h] *= s[h];                  // c3 -> c3*s  (s dead after this)
    }
  }

  // ---------- v-phase ----------
  {
    float v0[16], v1[16], v2[16];
#pragma unroll
    for (int h = 0; h < 16; ++h) { v0[h] = 0.f; v1[h] = 0.f; v2[h] = 0.f; }
    const float4* __restrict__ xp = (const float4*)(xsp + (size_t)node * 480 + 128);
    const float4* __restrict__ p1 = (const float4*)(ws + P1_OFF);
    for (int u4 = 0; u4 < 16; ++u4) {
      float4 A = xp[3*u4], B = xp[3*u4+1], C = xp[3*u4+2];
      const float4* __restrict__ row = p1 + (u4 << 4);
#pragma unroll
      for (int h = 0; h < 16; ++h) {
        float4 w = row[h];
        v0[h] = fmaf(A.x, w.x, v0[h]); v1[h] = fmaf(A.y, w.x, v1[h]); v2[h] = fmaf(A.z, w.x, v2[h]);
        v0[h] = fmaf(A.w, w.y, v0[h]); v1[h] = fmaf(B.x, w.y, v1[h]); v2[h] = fmaf(B.y, w.y, v2[h]);
        v0[h] = fmaf(B.z, w.z, v0[h]); v1[h] = fmaf(B.w, w.z, v1[h]); v2[h] = fmaf(C.x, w.z, v2[h]);
        v0[h] = fmaf(C.y, w.w, v0[h]); v1[h] = fmaf(C.z, w.w, v1[h]); v2[h] = fmaf(C.w, w.w, v2[h]);
      }
    }
#pragma unroll
    for (int h = 0; h < 16; ++h) {
      float a = v0[h], b = v1[h], d = v2[h];
      float nv = fmaf(a, a, fmaf(b, b, d * d));
      o0 = fmaf(c[16 + h], nv, o0);                        // c1*|v|^2
      float c4h = c[64 + h];
      o2m0 = fmaf(c4h, SQ2 * d * a, o2m0);                 // vv5[0]
      o2m1 = fmaf(c4h, SQ2 * a * b, o2m1);                 // vv5[1]
      o2m2 = fmaf(c4h, (2.f*b*b - d*d - a*a) * I6, o2m2);  // vv5[2]
      o2m3 = fmaf(c4h, SQ2 * b * d, o2m3);                 // vv5[3]
      o2m4 = fmaf(c4h, (d*d - a*a) * I2, o2m4);            // vv5[4]
    }
  }

  // ---------- t-phase ----------
  {
    float t0[16], t1[16], t2[16], t3[16], t4[16];
#pragma unroll
    for (int h = 0; h < 16; ++h) { t0[h]=0.f; t1[h]=0.f; t2[h]=0.f; t3[h]=0.f; t4[h]=0.f; }
    const float4* __restrict__ xp = (const float4*)(xsp + (size_t)node * 480 + 320);
    const float4* __restrict__ p2 = (const float4*)(ws + P2_OFF);
    for (int u4 = 0; u4 < 8; ++u4) {
      float4 A = xp[5*u4], B = xp[5*u4+1], C = xp[5*u4+2], D = xp[5*u4+3], E = xp[5*u4+4];
      const float4* __restrict__ row = p2 + (u4 << 4);
#pragma unroll
      for (int h = 0; h < 16; ++h) {
        float4 w = row[h];
        t0[h]=fmaf(A.x,w.x,t0[h]); t1[h]=fmaf(A.y,w.x,t1[h]); t2[h]=fmaf(A.z,w.x,t2[h]); t3[h]=fmaf(A.w,w.x,t3[h]); t4[h]=fmaf(B.x,w.x,t4[h]);
        t0[h]=fmaf(B.y,w.y,t0[h]); t1[h]=fmaf(B.z,w.y,t1[h]); t2[h]=fmaf(B.w,w.y,t2[h]); t3[h]=fmaf(C.x,w.y,t3[h]); t4[h]=fmaf(C.y,w.y,t4[h]);
        t0[h]=fmaf(C.z,w.z,t0[h]); t1[h]=fmaf(C.w,w.z,t1[h]); t2[h]=fmaf(D.x,w.z,t2[h]); t3[h]=fmaf(D.y,w.z,t3[h]); t4[h]=fmaf(D.z,w.z,t4[h]);
        t0[h]=fmaf(D.w,w.w,t0[h]); t1[h]=fmaf(E.x,w.w,t1[h]); t2[h]=fmaf(E.y,w.w,t2[h]); t3[h]=fmaf(E.z,w.w,t3[h]); t4[h]=fmaf(E.w,w.w,t4[h]);
      }
    }
#pragma unroll
    for (int h = 0; h < 16; ++h) {
      float q0=t0[h], q1=t1[h], q2=t2[h], q3=t3[h], q4=t4[h];
      float nt = fmaf(q0,q0, fmaf(q1,q1, fmaf(q2,q2, fmaf(q3,q3, q4*q4))));
      o0 = fmaf(c[32 + h], nt, o0);                        // c2*|t|^2
      float c3s = c[48 + h];                               // (c3*s)
      o2m0 = fmaf(c3s, q0, o2m0);
      o2m1 = fmaf(c3s, q1, o2m1);
      o2m2 = fmaf(c3s, q2, o2m2);
      o2m3 = fmaf(c3s, q3, o2m3);
      o2m4 = fmaf(c3s, q4, o2m4);
      // T (symmetric traceless) from t5, A = T*T
      float d0 = -q2*I6 - q4*I2;
      float d1 =  2.f*q2*I6;
      float d2 = -q2*I6 + q4*I2;
      float a = q1*I2, b = q0*I2, cc = q3*I2;
      float A00 = fmaf(d0,d0, fmaf(a,a, b*b));
      float A11 = fmaf(a,a, fmaf(d1,d1, cc*cc));
      float A22 = fmaf(b,b, fmaf(cc,cc, d2*d2));
      float A01 = fmaf(a, d0 + d1, b*cc);
      float A02 = fmaf(b, d0 + d2, a*cc);
      float A12 = fmaf(cc, d1 + d2, a*b);
      float c5h = c[80 + h];
      o2m0 = fmaf(c5h, SQ2 * A02, o2m0);
      o2m1 = fmaf(c5h, SQ2 * A01, o2m1);
      o2m2 = fmaf(c5h, (2.f*A11 - A22 - A00) * I6, o2m2);
      o2m3 = fmaf(c5h, SQ2 * A12, o2m3);
      o2m4 = fmaf(c5h, (A22 - A00) * I2, o2m4);
    }
  }

  // ---------- segment accumulate ----------
  int g = bidx[node];
  int gmin = bidx[blockIdx.x * TPB];
  int rel = g - gmin;
  float* __restrict__ ACC = ws + ACC_OFF;
  if (rel < SPAN) {
    atomicAdd(&accL[rel*6 + 0], o0);
    atomicAdd(&accL[rel*6 + 1], o2m0);
    atomicAdd(&accL[rel*6 + 2], o2m1);
    atomicAdd(&accL[rel*6 + 3], o2m2);
    atomicAdd(&accL[rel*6 + 4], o2m3);
    atomicAdd(&accL[rel*6 + 5], o2m4);
  } else {
    atomicAdd(&ACC[g*6 + 0], o0);
    atomicAdd(&ACC[g*6 + 1], o2m0);
    atomicAdd(&ACC[g*6 + 2], o2m1);
    atomicAdd(&ACC[g*6 + 3], o2m2);
    atomicAdd(&ACC[g*6 + 4], o2m3);
    atomicAdd(&ACC[g*6 + 5], o2m4);
  }
  __syncthreads();
  for (int i = tid; i < SPAN * 6; i += TPB) {
    float val = accL[i];
    if (val != 0.f) atomicAdd(&ACC[(gmin + i / 6) * 6 + (i % 6)], val);
  }
}

__global__ __launch_bounds__(64) void finalize_kernel(
    const float* __restrict__ ws, float* __restrict__ out)
{
  int g = blockIdx.x * 64 + threadIdx.x;
  if (g >= G_GRP) return;
  const float I2 = 0.70710678118f, I3 = 0.57735026919f, I6 = 0.40824829046f;
  const float* A = ws + ACC_OFF + g * 6;
  float g0 = A[0], q0 = A[1], q1 = A[2], q2 = A[3], q3 = A[4], q4 = A[5];
  float M00 = g0*I3 - q2*I6 - q4*I2;
  float M11 = g0*I3 + 2.f*q2*I6;
  float M22 = g0*I3 - q2*I6 + q4*I2;
  float M01 = q1*I2, M02 = q0*I2, M12 = q3*I2;
  float* o = out + g * 9;
  // out[a][b] = M[p[a]][p[b]], p = {2,0,1}
  o[0] = M22; o[1] = M02; o[2] = M12;
  o[3] = M02; o[4] = M00; o[5] = M01;
  o[6] = M12; o[7] = M01; o[8] = M11;
}

extern "C" void kernel_launch(void* const* d_in, const int* in_sizes, int n_in,
                              void* d_out, int out_size, void* d_ws, size_t ws_size,
                              hipStream_t stream)
{
  const float* xsc = (const float*)d_in[0];   // x_scalar  (N,128)
  const float* xsp = (const float*)d_in[1];   // x_spherical (N,480)
  // d_in[2] = coord (unused)
  const int*   bidx = (const int*)d_in[3];    // batch_index (N,)
  const float* W0  = (const float*)d_in[4];
  const float* W1  = (const float*)d_in[5];
  const float* W2  = (const float*)d_in[6];
  const float* Wg1 = (const float*)d_in[7];
  const float* bg1 = (const float*)d_in[8];
  const float* Wg2 = (const float*)d_in[9];
  const float* bg2 = (const float*)d_in[10];
  const float* wp0 = (const float*)d_in[11];
  const float* wp2 = (const float*)d_in[12];
  float* ws = (float*)d_ws;

  hipMemsetAsync(d_ws, 0, 3072 * sizeof(float), stream);
  repack_kernel<<<32, 256, 0, stream>>>(W0, W1, W2, Wg1, bg1, Wg2, bg2, wp0, wp2, ws);
  node_kernel<<<N_NODES / TPB, TPB, 0, stream>>>(xsc, xsp, bidx, ws);
  finalize_kernel<<<(G_GRP + 63) / 64, 64, 0, stream>>>(ws, (float*)d_out);
}